// Round 5
// baseline (24635.704 us; speedup 1.0000x reference)
//
#include <hip/hip_runtime.h>
#include <stddef.h>

typedef unsigned int u32;

#define TT 512
#define TC 64        // timestep chunk
#define NCHUNK 8

__device__ __forceinline__ float sigmoidf_(float x) {
    return 1.0f / (1.0f + __expf(-x));
}
__device__ __forceinline__ float tanhf_(float x) {
    float ax = fabsf(x);
    float e = __expf(-2.0f * ax);
    float t = (1.0f - e) / (1.0f + e);
    return copysignf(t, x);
}
__device__ __forceinline__ int swz(int k4) { return k4 ^ ((k4 >> 2) & 7); }

// ============================================================================
// proj_gemm: xW[tl][j][b] = sum_k W[j][k] * X[b*sXb + (t0+t)*sXt + k] + bih[j] + bhh[j]
//   M=2048 (gate rows j), N = TC*32 (t-local x batch), K=512
//   tile 128x128, K-chunk 32, 256 threads, 8x8 register tile.
// ============================================================================
#define APITCH 132
#define BPITCH 132

__global__ void __launch_bounds__(256, 2)
proj_gemm(const float* __restrict__ W,
          const float* __restrict__ bih, const float* __restrict__ bhh,
          const float* __restrict__ X, size_t sXb, size_t sXt, int t0,
          float* __restrict__ xW)
{
    __shared__ float As[32][APITCH];   // [k][m]
    __shared__ float Bs[32][BPITCH];   // [k][n]
    const int tid = threadIdx.x;
    const int mbase = blockIdx.x * 128;
    const int nt = blockIdx.y;                 // 0..15 (N-tile of 128 = 4 t x 32 b)
    const int tm = tid >> 4;                   // 0..15 -> 8 m's
    const int tn = tid & 15;                   // 0..15 -> 8 n's
    float acc[8][8] = {};

    for (int kc = 0; kc < 512; kc += 32) {
        __syncthreads();
        // stage A: 128 m x 32 k (transpose to [k][m])
#pragma unroll
        for (int u = 0; u < 4; ++u) {
            const int f = u * 256 + tid;
            const int m = f >> 3, k4 = f & 7;
            const float4 v = *(const float4*)(W + (size_t)(mbase + m) * 512 + kc + k4 * 4);
            As[k4 * 4 + 0][m] = v.x; As[k4 * 4 + 1][m] = v.y;
            As[k4 * 4 + 2][m] = v.z; As[k4 * 4 + 3][m] = v.w;
        }
        // stage B: 128 n x 32 k (transpose to [k][n]); n -> (tl = n>>5, b = n&31)
#pragma unroll
        for (int u = 0; u < 4; ++u) {
            const int f = u * 256 + tid;
            const int n = f >> 3, k4 = f & 7;
            const int tl = n >> 5, b = n & 31;
            const float4 v = *(const float4*)(X + (size_t)b * sXb +
                                              (size_t)(t0 + nt * 4 + tl) * sXt + kc + k4 * 4);
            Bs[k4 * 4 + 0][n] = v.x; Bs[k4 * 4 + 1][n] = v.y;
            Bs[k4 * 4 + 2][n] = v.z; Bs[k4 * 4 + 3][n] = v.w;
        }
        __syncthreads();
#pragma unroll 8
        for (int kk = 0; kk < 32; ++kk) {
            const float4 a0 = *(const float4*)&As[kk][tm * 8];
            const float4 a1 = *(const float4*)&As[kk][tm * 8 + 4];
            const float4 b0 = *(const float4*)&Bs[kk][tn * 8];
            const float4 b1 = *(const float4*)&Bs[kk][tn * 8 + 4];
            const float am[8] = {a0.x,a0.y,a0.z,a0.w,a1.x,a1.y,a1.z,a1.w};
            const float bn[8] = {b0.x,b0.y,b0.z,b0.w,b1.x,b1.y,b1.z,b1.w};
#pragma unroll
            for (int i = 0; i < 8; ++i)
#pragma unroll
                for (int j = 0; j < 8; ++j)
                    acc[i][j] = fmaf(am[i], bn[j], acc[i][j]);
        }
    }
    // epilogue: thread's 8 n are contiguous b within one t-local
    const int tl_loc = nt * 4 + (tn >> 2);
    const int bcol = (tn & 3) * 8;
#pragma unroll
    for (int i = 0; i < 8; ++i) {
        const int m = mbase + tm * 8 + i;
        const float bias = bih[m] + bhh[m];
        float* dst = xW + ((size_t)tl_loc * 2048 + m) * 32 + bcol;
        float4 v0 = {acc[i][0] + bias, acc[i][1] + bias, acc[i][2] + bias, acc[i][3] + bias};
        float4 v1 = {acc[i][4] + bias, acc[i][5] + bias, acc[i][6] + bias, acc[i][7] + bias};
        *(float4*)dst = v0;
        *(float4*)(dst + 4) = v1;
    }
}

// ============================================================================
// lstm_rec: recurrent half. 256 blocks x 512 threads, 1 block/CU, all resident.
//   bid: chain = bid&7 (4 batches), rb = bid>>3 (16 hidden units -> 64 gate rows).
//   W_hh in registers: thread (rg=tid>>5, kg=tid&31) holds rows rg*4..+3 (k-slice kg*16..+15).
//   gates[j][b] = xW[t][j][b](precomp, bias folded) + sum_k W_hh[j][k] h[b][k]
// ============================================================================
__global__ void __launch_bounds__(512, 2)
lstm_rec(const float* __restrict__ Whh,      // [2048][512]
         const float* __restrict__ xW,       // [TC][2048][32]
         float* __restrict__ hbuf,           // h at hbuf + t*sT + b*sB + hh
         size_t sT, size_t sB,
         float* __restrict__ cst,            // [32][512] c-state for this layer
         u32* __restrict__ cnt,              // [8][512] flags for this layer
         int t0)
{
    __shared__ float xh[4][512];             // 8KB, quad-swizzled h(t-1)
    __shared__ float part[256 * 36];         // 36KB partials: [rl*4+b][kg]
    __shared__ float gl[16][4][4];           // [hl][b][gate]

    const int tid = threadIdx.x;
    const int chain = blockIdx.x & 7;        // cluster chain on one XCD
    const int rb = blockIdx.x >> 3;
    const int hb = rb * 16;                  // hidden slice [hb, hb+16)
    const int bb = chain * 4;                // batch slice [bb, bb+4)

    const int rg = tid >> 5;                 // 0..15
    const int kg = tid & 31;                 // 0..31

    // ---- load W_hh slice into registers (once) ----
    float w[4][16];
#pragma unroll
    for (int i = 0; i < 4; ++i) {
        const int rl = rg * 4 + i;
        const int j = ((rl >> 4) << 9) + hb + (rl & 15);
#pragma unroll
        for (int s4 = 0; s4 < 4; ++s4) {
            const float4 v = *(const float4*)(Whh + (size_t)j * 512 + kg * 16 + s4 * 4);
            w[i][s4 * 4 + 0] = v.x; w[i][s4 * 4 + 1] = v.y;
            w[i][s4 * 4 + 2] = v.z; w[i][s4 * 4 + 3] = v.w;
        }
    }
    // reduce-cell decode (tid<256): one output (rl, b) per thread
    const int rl_c = tid >> 2, b_c = tid & 3;
    const int j_c = ((rl_c >> 4) << 9) + hb + (rl_c & 15);
    // update decode (tid<64)
    const int hl_u = tid >> 2, b_u = tid & 3;
    float c_reg = 0.0f;
    if (tid < 64) c_reg = cst[(size_t)(bb + b_u) * 512 + hb + hl_u];

    __syncthreads();

    for (int t = t0; t < t0 + TC; ++t) {
        // prefetch precomputed input-projection (independent of the flag)
        float xwv = 0.0f;
        if (tid < 256)
            xwv = xW[((size_t)(t - t0) * 2048 + j_c) * 32 + bb + b_c];

        if (t > 0) {
            // wait for all 32 row-blocks of this chain to publish h(t-1)
            if (tid == 0) {
                u32* f = &cnt[chain * 512 + (t - 1)];
                while (__hip_atomic_load(f, __ATOMIC_ACQUIRE, __HIP_MEMORY_SCOPE_AGENT) < 32u)
                    __builtin_amdgcn_s_sleep(2);
            }
            __builtin_amdgcn_fence(__ATOMIC_ACQUIRE, "agent");
            __syncthreads();
            // stage h(t-1): one float4 per thread, XOR quad-swizzle
            const int b_s = tid >> 7, k4 = tid & 127;
            const float4 hv = *(const float4*)(hbuf + (size_t)(t - 1) * sT +
                                               (size_t)(bb + b_s) * sB + (size_t)k4 * 4);
            *(float4*)&xh[b_s][swz(k4) << 2] = hv;
        }
        __syncthreads();

        float acc[4][4] = {};
        if (t > 0) {
#pragma unroll
            for (int s4 = 0; s4 < 4; ++s4) {
                const int q = swz((kg << 2) + s4) << 2;
                const float4 x0 = *(const float4*)&xh[0][q];
                const float4 x1 = *(const float4*)&xh[1][q];
                const float4 x2 = *(const float4*)&xh[2][q];
                const float4 x3 = *(const float4*)&xh[3][q];
#pragma unroll
                for (int i = 0; i < 4; ++i) {
                    acc[i][0] = fmaf(w[i][s4*4+0], x0.x, acc[i][0]);
                    acc[i][0] = fmaf(w[i][s4*4+1], x0.y, acc[i][0]);
                    acc[i][0] = fmaf(w[i][s4*4+2], x0.z, acc[i][0]);
                    acc[i][0] = fmaf(w[i][s4*4+3], x0.w, acc[i][0]);
                    acc[i][1] = fmaf(w[i][s4*4+0], x1.x, acc[i][1]);
                    acc[i][1] = fmaf(w[i][s4*4+1], x1.y, acc[i][1]);
                    acc[i][1] = fmaf(w[i][s4*4+2], x1.z, acc[i][1]);
                    acc[i][1] = fmaf(w[i][s4*4+3], x1.w, acc[i][1]);
                    acc[i][2] = fmaf(w[i][s4*4+0], x2.x, acc[i][2]);
                    acc[i][2] = fmaf(w[i][s4*4+1], x2.y, acc[i][2]);
                    acc[i][2] = fmaf(w[i][s4*4+2], x2.z, acc[i][2]);
                    acc[i][2] = fmaf(w[i][s4*4+3], x2.w, acc[i][2]);
                    acc[i][3] = fmaf(w[i][s4*4+0], x3.x, acc[i][3]);
                    acc[i][3] = fmaf(w[i][s4*4+1], x3.y, acc[i][3]);
                    acc[i][3] = fmaf(w[i][s4*4+2], x3.z, acc[i][3]);
                    acc[i][3] = fmaf(w[i][s4*4+3], x3.w, acc[i][3]);
                }
            }
        }
        // partials -> LDS (pitch 36 floats, 2-way max)
#pragma unroll
        for (int i = 0; i < 4; ++i)
#pragma unroll
            for (int b = 0; b < 4; ++b)
                part[(size_t)(((rg * 4 + i) * 4) + b) * 36 + kg] = acc[i][b];
        __syncthreads();
        // reduce 32 partials per output cell, add xW, stash per-gate
        if (tid < 256) {
            const float* row = &part[(size_t)tid * 36];
            const float4 p0 = *(const float4*)(row + 0);
            const float4 p1 = *(const float4*)(row + 4);
            const float4 p2 = *(const float4*)(row + 8);
            const float4 p3 = *(const float4*)(row + 12);
            const float4 p4 = *(const float4*)(row + 16);
            const float4 p5 = *(const float4*)(row + 20);
            const float4 p6 = *(const float4*)(row + 24);
            const float4 p7 = *(const float4*)(row + 28);
            const float s0 = ((p0.x + p0.y) + (p0.z + p0.w)) + ((p1.x + p1.y) + (p1.z + p1.w));
            const float s1 = ((p2.x + p2.y) + (p2.z + p2.w)) + ((p3.x + p3.y) + (p3.z + p3.w));
            const float s2 = ((p4.x + p4.y) + (p4.z + p4.w)) + ((p5.x + p5.y) + (p5.z + p5.w));
            const float s3 = ((p6.x + p6.y) + (p6.z + p6.w)) + ((p7.x + p7.y) + (p7.z + p7.w));
            const float gate = ((s0 + s1) + (s2 + s3)) + xwv;
            gl[rl_c & 15][b_c][rl_c >> 4] = gate;
        }
        __syncthreads();
        if (tid < 64) {
            const float4 gv = *(const float4*)&gl[hl_u][b_u][0];
            const float i_ = sigmoidf_(gv.x);
            const float f_ = sigmoidf_(gv.y);
            const float g_ = tanhf_(gv.z);
            const float o_ = sigmoidf_(gv.w);
            c_reg = f_ * c_reg + i_ * g_;
            const float hv = o_ * tanhf_(c_reg);
            __hip_atomic_store(hbuf + (size_t)t * sT + (size_t)(bb + b_u) * sB + hb + hl_u,
                               hv, __ATOMIC_RELAXED, __HIP_MEMORY_SCOPE_AGENT);
            __builtin_amdgcn_fence(__ATOMIC_RELEASE, "agent");
            if (tid == 0)
                __hip_atomic_fetch_add(&cnt[chain * 512 + t], 1u,
                                       __ATOMIC_RELEASE, __HIP_MEMORY_SCOPE_AGENT);
        }
        __syncthreads();
    }
    if (tid < 64) cst[(size_t)(bb + b_u) * 512 + hb + hl_u] = c_reg;
}

// ============================================================================
extern "C" void kernel_launch(void* const* d_in, const int* in_sizes, int n_in,
                              void* d_out, int out_size, void* d_ws, size_t ws_size,
                              hipStream_t stream) {
    const float* inp  = (const float*)d_in[0];
    const float* Wih0 = (const float*)d_in[1];
    const float* Whh0 = (const float*)d_in[2];
    const float* bih0 = (const float*)d_in[3];
    const float* bhh0 = (const float*)d_in[4];
    const float* Wih1 = (const float*)d_in[5];
    const float* Whh1 = (const float*)d_in[6];
    const float* bih1 = (const float*)d_in[7];
    const float* bhh1 = (const float*)d_in[8];
    float* out = (float*)d_out;

    char* ws = (char*)d_ws;
    float* h0seq = (float*)ws;                              // [512][32][512]  32 MB
    float* xW    = (float*)(ws + 33554432);                 // [64][2048][32]  16 MB
    float* cst   = (float*)(ws + 50331648);                 // [2][32][512]   128 KB
    u32*   cnt   = (u32*)  (ws + 50331648 + 131072);        // [2][8][512]     32 KB
    (void)hipMemsetAsync(ws + 50331648, 0, 163840, stream); // zero c-state + flags

    const dim3 gg(16, 16), gb(256);
    const dim3 rg(256), rb(512);

    // layer 0: x-projection GEMM + recurrence, chunked over T
    for (int c = 0; c < NCHUNK; ++c) {
        const int t0 = c * TC;
        hipLaunchKernelGGL(proj_gemm, gg, gb, 0, stream,
                           Wih0, bih0, bhh0, inp, (size_t)512 * 512, (size_t)512, t0, xW);
        hipLaunchKernelGGL(lstm_rec, rg, rb, 0, stream,
                           Whh0, xW, h0seq, (size_t)32 * 512, (size_t)512,
                           cst, cnt, t0);
    }
    // layer 1: input = h0seq; h published directly into d_out ([B][T][H])
    for (int c = 0; c < NCHUNK; ++c) {
        const int t0 = c * TC;
        hipLaunchKernelGGL(proj_gemm, gg, gb, 0, stream,
                           Wih1, bih1, bhh1, h0seq, (size_t)512, (size_t)32 * 512, t0, xW);
        hipLaunchKernelGGL(lstm_rec, rg, rb, 0, stream,
                           Whh1, xW, out, (size_t)512, (size_t)512 * 512,
                           cst + 32 * 512, cnt + 8 * 512, t0);
    }
}

// Round 6
// 8656.988 us; speedup vs baseline: 2.8458x; 2.8458x over previous
//
#include <hip/hip_runtime.h>
#include <stddef.h>

typedef unsigned int u32;

#define TT 512
#define TC 64        // timestep chunk
#define NCHUNK 8

__device__ __forceinline__ float sigmoidf_(float x) {
    return 1.0f / (1.0f + __expf(-x));
}
__device__ __forceinline__ float tanhf_(float x) {
    float ax = fabsf(x);
    float e = __expf(-2.0f * ax);
    float t = (1.0f - e) / (1.0f + e);
    return copysignf(t, x);
}
__device__ __forceinline__ int swz(int k4) { return k4 ^ ((k4 >> 2) & 7); }

// ---- per-access coherent (IF$-level) load/store: no cache-wide inv/wb needed ----
__device__ __forceinline__ float4 ldg_cv4(const float* p) {
    float4 v;
    asm volatile("global_load_dwordx4 %0, %1, off sc0 sc1\n\t"
                 "s_waitcnt vmcnt(0)"
                 : "=v"(v) : "v"(p) : "memory");
    return v;
}
__device__ __forceinline__ void stg_cv1(float* p, float v) {
    asm volatile("global_store_dword %0, %1, off sc0 sc1"
                 :: "v"(p), "v"(v) : "memory");
}

// ============================================================================
// proj_gemm: xW[tl][j][b] = sum_k W[j][k] * X[b*sXb + (t0+t)*sXt + k] + bih[j] + bhh[j]
//   M=2048 (gate rows j), N = TC*32 (t-local x batch), K=512
//   tile 128x128, K-chunk 32, 256 threads, 8x8 register tile.
// ============================================================================
#define APITCH 132
#define BPITCH 132

__global__ void __launch_bounds__(256, 2)
proj_gemm(const float* __restrict__ W,
          const float* __restrict__ bih, const float* __restrict__ bhh,
          const float* __restrict__ X, size_t sXb, size_t sXt, int t0,
          float* __restrict__ xW)
{
    __shared__ float As[32][APITCH];   // [k][m]
    __shared__ float Bs[32][BPITCH];   // [k][n]
    const int tid = threadIdx.x;
    const int mbase = blockIdx.x * 128;
    const int nt = blockIdx.y;                 // 0..15 (N-tile of 128 = 4 t x 32 b)
    const int tm = tid >> 4;                   // 0..15 -> 8 m's
    const int tn = tid & 15;                   // 0..15 -> 8 n's
    float acc[8][8] = {};

    for (int kc = 0; kc < 512; kc += 32) {
        __syncthreads();
        // stage A: 128 m x 32 k (transpose to [k][m])
#pragma unroll
        for (int u = 0; u < 4; ++u) {
            const int f = u * 256 + tid;
            const int m = f >> 3, k4 = f & 7;
            const float4 v = *(const float4*)(W + (size_t)(mbase + m) * 512 + kc + k4 * 4);
            As[k4 * 4 + 0][m] = v.x; As[k4 * 4 + 1][m] = v.y;
            As[k4 * 4 + 2][m] = v.z; As[k4 * 4 + 3][m] = v.w;
        }
        // stage B: 128 n x 32 k (transpose to [k][n]); n -> (tl = n>>5, b = n&31)
#pragma unroll
        for (int u = 0; u < 4; ++u) {
            const int f = u * 256 + tid;
            const int n = f >> 3, k4 = f & 7;
            const int tl = n >> 5, b = n & 31;
            const float4 v = *(const float4*)(X + (size_t)b * sXb +
                                              (size_t)(t0 + nt * 4 + tl) * sXt + kc + k4 * 4);
            Bs[k4 * 4 + 0][n] = v.x; Bs[k4 * 4 + 1][n] = v.y;
            Bs[k4 * 4 + 2][n] = v.z; Bs[k4 * 4 + 3][n] = v.w;
        }
        __syncthreads();
#pragma unroll 8
        for (int kk = 0; kk < 32; ++kk) {
            const float4 a0 = *(const float4*)&As[kk][tm * 8];
            const float4 a1 = *(const float4*)&As[kk][tm * 8 + 4];
            const float4 b0 = *(const float4*)&Bs[kk][tn * 8];
            const float4 b1 = *(const float4*)&Bs[kk][tn * 8 + 4];
            const float am[8] = {a0.x,a0.y,a0.z,a0.w,a1.x,a1.y,a1.z,a1.w};
            const float bn[8] = {b0.x,b0.y,b0.z,b0.w,b1.x,b1.y,b1.z,b1.w};
#pragma unroll
            for (int i = 0; i < 8; ++i)
#pragma unroll
                for (int j = 0; j < 8; ++j)
                    acc[i][j] = fmaf(am[i], bn[j], acc[i][j]);
        }
    }
    // epilogue: thread's 8 n are contiguous b within one t-local
    const int tl_loc = nt * 4 + (tn >> 2);
    const int bcol = (tn & 3) * 8;
#pragma unroll
    for (int i = 0; i < 8; ++i) {
        const int m = mbase + tm * 8 + i;
        const float bias = bih[m] + bhh[m];
        float* dst = xW + ((size_t)tl_loc * 2048 + m) * 32 + bcol;
        float4 v0 = {acc[i][0] + bias, acc[i][1] + bias, acc[i][2] + bias, acc[i][3] + bias};
        float4 v1 = {acc[i][4] + bias, acc[i][5] + bias, acc[i][6] + bias, acc[i][7] + bias};
        *(float4*)dst = v0;
        *(float4*)(dst + 4) = v1;
    }
}

// ============================================================================
// lstm_rec: recurrent half. 256 blocks x 512 threads, all resident.
//   chain = bid&7 (4 batches), rb = bid>>3 (16 hidden -> 64 gate rows).
//   W_hh in registers: thread (rg=tid>>5, kg=tid&31): rows rg*4..+3, k-slice kg*16..+15.
//   Fence-free sync: h via sc0sc1 loads/stores (coherent point), relaxed flags,
//   s_waitcnt vmcnt(0) between h-publish and flag-add. No buffer_inv/wbl2 in loop.
// ============================================================================
__global__ void __launch_bounds__(512, 1)
lstm_rec(const float* __restrict__ Whh,      // [2048][512]
         const float* __restrict__ xW,       // [TC][2048][32]
         float* __restrict__ hbuf,           // h at hbuf + t*sT + b*sB + hh
         size_t sT, size_t sB,
         float* __restrict__ cst,            // [32][512] c-state for this layer
         u32* __restrict__ cnt,              // [8][512] flags for this layer
         int t0)
{
    __shared__ float xh[4][512];             // 8KB, quad-swizzled h(t-1)
    __shared__ float gl[16][4][4];           // [hl][b][gate] 1KB

    const int tid = threadIdx.x;
    const int chain = blockIdx.x & 7;
    const int rb = blockIdx.x >> 3;
    const int hb = rb * 16;                  // hidden slice [hb, hb+16)
    const int bb = chain * 4;                // batch slice [bb, bb+4)

    const int rg = tid >> 5;                 // 0..15
    const int kg = tid & 31;                 // 0..31

    // ---- load W_hh slice into registers (once) ----
    float w[4][16];
#pragma unroll
    for (int i = 0; i < 4; ++i) {
        const int rl = rg * 4 + i;
        const int j = ((rl >> 4) << 9) + hb + (rl & 15);
#pragma unroll
        for (int s4 = 0; s4 < 4; ++s4) {
            const float4 v = *(const float4*)(Whh + (size_t)j * 512 + kg * 16 + s4 * 4);
            w[i][s4 * 4 + 0] = v.x; w[i][s4 * 4 + 1] = v.y;
            w[i][s4 * 4 + 2] = v.z; w[i][s4 * 4 + 3] = v.w;
        }
    }
    // gate-owner decode (kg<16): output (rl_o = rg*4 + kg>>2, b_o = kg&3)
    const int rl_o = rg * 4 + (kg >> 2);
    const int b_o  = kg & 3;
    const int j_o  = ((rl_o >> 4) << 9) + hb + (rl_o & 15);
    // update decode (tid<64)
    const int hl_u = tid >> 2, b_u = tid & 3;
    float c_reg = 0.0f;
    if (tid < 64) c_reg = cst[(size_t)(bb + b_u) * 512 + hb + hl_u];

    u32* flags = cnt + chain * 512;
    __syncthreads();

    for (int t = t0; t < t0 + TC; ++t) {
        // prefetch precomputed input-projection (plain cached load, no dependency)
        float xwv = 0.0f;
        if (kg < 16)
            xwv = xW[((size_t)(t - t0) * 2048 + j_o) * 32 + bb + b_o];

        if (t > 0) {
            if (tid == 0) {
                while (__hip_atomic_load(&flags[t - 1], __ATOMIC_RELAXED,
                                         __HIP_MEMORY_SCOPE_AGENT) < 32u)
                    __builtin_amdgcn_s_sleep(1);
            }
            __syncthreads();
            // stage h(t-1): one coherent float4 per thread, XOR quad-swizzle
            const int b_s = tid >> 7, k4 = tid & 127;
            const float4 hv = ldg_cv4(hbuf + (size_t)(t - 1) * sT +
                                      (size_t)(bb + b_s) * sB + (size_t)k4 * 4);
            *(float4*)&xh[b_s][swz(k4) << 2] = hv;
        }
        __syncthreads();

        float acc[4][4] = {};
        if (t > 0) {
#pragma unroll
            for (int s4 = 0; s4 < 4; ++s4) {
                const int q = swz((kg << 2) + s4) << 2;
                const float4 x0 = *(const float4*)&xh[0][q];
                const float4 x1 = *(const float4*)&xh[1][q];
                const float4 x2 = *(const float4*)&xh[2][q];
                const float4 x3 = *(const float4*)&xh[3][q];
#pragma unroll
                for (int i = 0; i < 4; ++i) {
                    acc[i][0] = fmaf(w[i][s4*4+0], x0.x, acc[i][0]);
                    acc[i][0] = fmaf(w[i][s4*4+1], x0.y, acc[i][0]);
                    acc[i][0] = fmaf(w[i][s4*4+2], x0.z, acc[i][0]);
                    acc[i][0] = fmaf(w[i][s4*4+3], x0.w, acc[i][0]);
                    acc[i][1] = fmaf(w[i][s4*4+0], x1.x, acc[i][1]);
                    acc[i][1] = fmaf(w[i][s4*4+1], x1.y, acc[i][1]);
                    acc[i][1] = fmaf(w[i][s4*4+2], x1.z, acc[i][1]);
                    acc[i][1] = fmaf(w[i][s4*4+3], x1.w, acc[i][1]);
                    acc[i][2] = fmaf(w[i][s4*4+0], x2.x, acc[i][2]);
                    acc[i][2] = fmaf(w[i][s4*4+1], x2.y, acc[i][2]);
                    acc[i][2] = fmaf(w[i][s4*4+2], x2.z, acc[i][2]);
                    acc[i][2] = fmaf(w[i][s4*4+3], x2.w, acc[i][2]);
                    acc[i][3] = fmaf(w[i][s4*4+0], x3.x, acc[i][3]);
                    acc[i][3] = fmaf(w[i][s4*4+1], x3.y, acc[i][3]);
                    acc[i][3] = fmaf(w[i][s4*4+2], x3.z, acc[i][3]);
                    acc[i][3] = fmaf(w[i][s4*4+3], x3.w, acc[i][3]);
                }
            }
        }
        // in-wave butterfly reduce over the 32 k-slices (half-wave groups, no LDS)
#pragma unroll
        for (int m = 1; m < 32; m <<= 1) {
#pragma unroll
            for (int i = 0; i < 4; ++i)
#pragma unroll
                for (int b = 0; b < 4; ++b)
                    acc[i][b] += __shfl_xor(acc[i][b], m);
        }
        if (kg < 16) {
            const float gate = acc[kg >> 2][b_o] + xwv;
            gl[rl_o & 15][b_o][rl_o >> 4] = gate;
        }
        __syncthreads();
        if (tid < 64) {  // one thread per (batch, hidden) pair
            const float4 gv = *(const float4*)&gl[hl_u][b_u][0];
            const float i_ = sigmoidf_(gv.x);
            const float f_ = sigmoidf_(gv.y);
            const float g_ = tanhf_(gv.z);
            const float o_ = sigmoidf_(gv.w);
            c_reg = f_ * c_reg + i_ * g_;
            const float hv = o_ * tanhf_(c_reg);
            stg_cv1(hbuf + (size_t)t * sT + (size_t)(bb + b_u) * sB + hb + hl_u, hv);
            asm volatile("s_waitcnt vmcnt(0)" ::: "memory");   // stores at coherent point
            if (tid == 0)
                __hip_atomic_fetch_add(&flags[t], 1u,
                                       __ATOMIC_RELAXED, __HIP_MEMORY_SCOPE_AGENT);
        }
        __syncthreads();
    }
    if (tid < 64) cst[(size_t)(bb + b_u) * 512 + hb + hl_u] = c_reg;
}

// ============================================================================
extern "C" void kernel_launch(void* const* d_in, const int* in_sizes, int n_in,
                              void* d_out, int out_size, void* d_ws, size_t ws_size,
                              hipStream_t stream) {
    const float* inp  = (const float*)d_in[0];
    const float* Wih0 = (const float*)d_in[1];
    const float* Whh0 = (const float*)d_in[2];
    const float* bih0 = (const float*)d_in[3];
    const float* bhh0 = (const float*)d_in[4];
    const float* Wih1 = (const float*)d_in[5];
    const float* Whh1 = (const float*)d_in[6];
    const float* bih1 = (const float*)d_in[7];
    const float* bhh1 = (const float*)d_in[8];
    float* out = (float*)d_out;

    char* ws = (char*)d_ws;
    float* h0seq = (float*)ws;                              // [512][32][512]  32 MB
    float* xW    = (float*)(ws + 33554432);                 // [64][2048][32]  16 MB
    float* cst   = (float*)(ws + 50331648);                 // [2][32][512]   128 KB
    u32*   cnt   = (u32*)  (ws + 50331648 + 131072);        // [2][8][512]     32 KB
    (void)hipMemsetAsync(ws + 50331648, 0, 163840, stream); // zero c-state + flags

    const dim3 gg(16, 16), gb(256);
    const dim3 rg(256), rb(512);

    // layer 0: x-projection GEMM + recurrence, chunked over T
    for (int c = 0; c < NCHUNK; ++c) {
        const int t0 = c * TC;
        hipLaunchKernelGGL(proj_gemm, gg, gb, 0, stream,
                           Wih0, bih0, bhh0, inp, (size_t)512 * 512, (size_t)512, t0, xW);
        hipLaunchKernelGGL(lstm_rec, rg, rb, 0, stream,
                           Whh0, xW, h0seq, (size_t)32 * 512, (size_t)512,
                           cst, cnt, t0);
    }
    // layer 1: input = h0seq; h published directly into d_out ([B][T][H])
    for (int c = 0; c < NCHUNK; ++c) {
        const int t0 = c * TC;
        hipLaunchKernelGGL(proj_gemm, gg, gb, 0, stream,
                           Wih1, bih1, bhh1, h0seq, (size_t)512, (size_t)32 * 512, t0, xW);
        hipLaunchKernelGGL(lstm_rec, rg, rb, 0, stream,
                           Whh1, xW, out, (size_t)512, (size_t)512 * 512,
                           cst + 32 * 512, cnt + 8 * 512, t0);
    }
}